// Round 1
// baseline (1388.717 us; speedup 1.0000x reference)
//
#include <hip/hip_runtime.h>

// AMG encoder: 262144 points x 64 grids x 2 features, trilinear grid_sample
// (align_corners=True, padding zeros), out[n, g*2+f] f32.
//
// Pass 1 (repack): [G,F,D,H,W] -> [G,D,H,W,F] (float2 per voxel) in d_ws.
// Pass 2 (sample): wave lane = grid id, one point per wave-iteration;
//                  8 float2 corner loads per (point,grid); coalesced 512B
//                  output row per point per wave.

constexpr int NPTS  = 262144;
constexpr int GVOX  = 64 * 64 * 64;   // 262144 voxels per grid
constexpr int PTS_PER_THREAD = 8;     // points per wave (per thread)

__global__ __launch_bounds__(256) void repack_kernel(
    const float* __restrict__ src, float4* __restrict__ dst)
{
    // 64 grids * 65536 quads = 4,194,304 threads; each handles 4 voxels.
    int tid = blockIdx.x * 256 + threadIdx.x;
    int g = tid >> 16;          // grid id
    int q = tid & 65535;        // quad id within grid
    const float* p0 = src + (size_t)g * (2 * GVOX) + q * 4;
    float4 a = *reinterpret_cast<const float4*>(p0);         // feature 0, 4 voxels
    float4 b = *reinterpret_cast<const float4*>(p0 + GVOX);  // feature 1, 4 voxels
    float4* o = dst + (((size_t)g * GVOX) >> 1) + (size_t)q * 2;
    o[0] = make_float4(a.x, b.x, a.y, b.y);
    o[1] = make_float4(a.z, b.z, a.w, b.w);
}

template <bool PACKED>
__global__ __launch_bounds__(256) void sample_kernel(
    const float* __restrict__ xs, const float* __restrict__ Ms,
    const float* __restrict__ grids, float* __restrict__ out)
{
    const int g   = threadIdx.x & 63;   // lane = grid id
    const int wid = threadIdx.x >> 6;   // wave id in block (0..3)

    // Per-lane transform rows (12 coeffs), read once; L2-broadcast across blocks.
    const float* Mg = Ms + g * 16;
    const float m00 = Mg[0], m01 = Mg[1], m02 = Mg[2],  m03 = Mg[3];
    const float m10 = Mg[4], m11 = Mg[5], m12 = Mg[6],  m13 = Mg[7];
    const float m20 = Mg[8], m21 = Mg[9], m22 = Mg[10], m23 = Mg[11];

    const float2* __restrict__ gp = reinterpret_cast<const float2*>(grids) + (size_t)g * GVOX;
    const float*  __restrict__ g0 = grids + (size_t)g * 2 * GVOX;
    const float*  __restrict__ g1 = g0 + GVOX;

    const int n0 = blockIdx.x * (4 * PTS_PER_THREAD) + wid * PTS_PER_THREAD;

    #pragma unroll
    for (int i = 0; i < PTS_PER_THREAD; ++i) {
        const int n = n0 + i;
        const float cx = xs[n * 3 + 0];
        const float cy = xs[n * 3 + 1];
        const float cz = xs[n * 3 + 2];

        // pts = M[g] @ [x,y,z,1]; px->W, py->H, pz->D; align_corners scale.
        const float px = (fmaf(m00, cx, fmaf(m01, cy, fmaf(m02, cz, m03))) + 1.0f) * 31.5f;
        const float py = (fmaf(m10, cx, fmaf(m11, cy, fmaf(m12, cz, m13))) + 1.0f) * 31.5f;
        const float pz = (fmaf(m20, cx, fmaf(m21, cy, fmaf(m22, cz, m23))) + 1.0f) * 31.5f;

        const float flx = floorf(px), fly = floorf(py), flz = floorf(pz);
        const float fx = px - flx, fy = py - fly, fz = pz - flz;
        const int x0 = (int)flx, y0 = (int)fly, z0 = (int)flz;

        // Per-axis weights with zero-padding validity folded in.
        const float wx0 = (x0 >= 0  && x0 < 64) ? (1.0f - fx) : 0.0f;
        const float wx1 = (x0 >= -1 && x0 < 63) ? fx          : 0.0f;
        const float wy0 = (y0 >= 0  && y0 < 64) ? (1.0f - fy) : 0.0f;
        const float wy1 = (y0 >= -1 && y0 < 63) ? fy          : 0.0f;
        const float wz0 = (z0 >= 0  && z0 < 64) ? (1.0f - fz) : 0.0f;
        const float wz1 = (z0 >= -1 && z0 < 63) ? fz          : 0.0f;

        const int xc0 = min(max(x0, 0), 63), xc1 = min(max(x0 + 1, 0), 63);
        const int yc0 = min(max(y0, 0), 63), yc1 = min(max(y0 + 1, 0), 63);
        const int zc0 = min(max(z0, 0), 63), zc1 = min(max(z0 + 1, 0), 63);

        const int r00 = (zc0 * 64 + yc0) * 64, r01 = (zc0 * 64 + yc1) * 64;
        const int r10 = (zc1 * 64 + yc0) * 64, r11 = (zc1 * 64 + yc1) * 64;

        const float waa = wz0 * wy0, wab = wz0 * wy1;
        const float wba = wz1 * wy0, wbb = wz1 * wy1;
        const float pA0 = waa * wx0, pA1 = waa * wx1;
        const float pB0 = wab * wx0, pB1 = wab * wx1;
        const float pC0 = wba * wx0, pC1 = wba * wx1;
        const float pD0 = wbb * wx0, pD1 = wbb * wx1;

        float acc0, acc1;
        if constexpr (PACKED) {
            const float2 vA0 = gp[r00 + xc0], vA1 = gp[r00 + xc1];
            const float2 vB0 = gp[r01 + xc0], vB1 = gp[r01 + xc1];
            const float2 vC0 = gp[r10 + xc0], vC1 = gp[r10 + xc1];
            const float2 vD0 = gp[r11 + xc0], vD1 = gp[r11 + xc1];
            acc0 = vA0.x * pA0 + vA1.x * pA1 + vB0.x * pB0 + vB1.x * pB1
                 + vC0.x * pC0 + vC1.x * pC1 + vD0.x * pD0 + vD1.x * pD1;
            acc1 = vA0.y * pA0 + vA1.y * pA1 + vB0.y * pB0 + vB1.y * pB1
                 + vC0.y * pC0 + vC1.y * pC1 + vD0.y * pD0 + vD1.y * pD1;
        } else {
            acc0 = g0[r00 + xc0] * pA0 + g0[r00 + xc1] * pA1
                 + g0[r01 + xc0] * pB0 + g0[r01 + xc1] * pB1
                 + g0[r10 + xc0] * pC0 + g0[r10 + xc1] * pC1
                 + g0[r11 + xc0] * pD0 + g0[r11 + xc1] * pD1;
            acc1 = g1[r00 + xc0] * pA0 + g1[r00 + xc1] * pA1
                 + g1[r01 + xc0] * pB0 + g1[r01 + xc1] * pB1
                 + g1[r10 + xc0] * pC0 + g1[r10 + xc1] * pC1
                 + g1[r11 + xc0] * pD0 + g1[r11 + xc1] * pD1;
        }

        // Coalesced: 64 lanes write one contiguous 512B output row for point n.
        *reinterpret_cast<float2*>(out + (size_t)n * 128 + g * 2) =
            make_float2(acc0, acc1);
    }
}

extern "C" void kernel_launch(void* const* d_in, const int* in_sizes, int n_in,
                              void* d_out, int out_size, void* d_ws, size_t ws_size,
                              hipStream_t stream)
{
    const float* xs = (const float*)d_in[0];
    const float* Ms = (const float*)d_in[1];
    const float* fg = (const float*)d_in[2];
    float* out = (float*)d_out;

    const size_t packed_bytes = (size_t)64 * GVOX * sizeof(float2);  // 134 MB
    const int sample_blocks = NPTS / (4 * PTS_PER_THREAD);           // 8192

    if (ws_size >= packed_bytes) {
        repack_kernel<<<16384, 256, 0, stream>>>(fg, (float4*)d_ws);
        sample_kernel<true><<<sample_blocks, 256, 0, stream>>>(
            xs, Ms, (const float*)d_ws, out);
    } else {
        sample_kernel<false><<<sample_blocks, 256, 0, stream>>>(
            xs, Ms, fg, out);
    }
}

// Round 2
// 597.637 us; speedup vs baseline: 2.3237x; 2.3237x over previous
//
#include <hip/hip_runtime.h>

// AMG encoder: 262144 points x 64 grids x 2 features, trilinear grid_sample
// (align_corners=True, zero padding), out[n, g*2+f] f32.
//
// Pipeline:
//   1. repack grids [G,F,D,H,W] -> [G,D,H,W,F] (float2/voxel) in ws
//   2. morton-sort points into 16^3 cells (hist -> scan -> scatter)
//   3. sample: block = 256 consecutive sorted points, inner loop over all
//      64 grids in phases of 8; per-thread register-staged 64B output line
//      per phase. Sorted points => per-(block,grid) footprint ~6-10KB => L1
//      reuse; XCD-chunked swizzle keeps morton neighbors on one XCD L2.

constexpr int NPTS  = 262144;
constexpr int GVOX  = 64 * 64 * 64;
constexpr int NCELL = 4096;            // 16^3 morton cells

// ---------------- repack ----------------
__global__ __launch_bounds__(256) void repack_kernel(
    const float* __restrict__ src, float4* __restrict__ dst)
{
    int tid = blockIdx.x * 256 + threadIdx.x;
    int g = tid >> 16;
    int q = tid & 65535;
    const float* p0 = src + (size_t)g * (2 * GVOX) + q * 4;
    float4 a = *reinterpret_cast<const float4*>(p0);
    float4 b = *reinterpret_cast<const float4*>(p0 + GVOX);
    float4* o = dst + (((size_t)g * GVOX) >> 1) + (size_t)q * 2;
    o[0] = make_float4(a.x, b.x, a.y, b.y);
    o[1] = make_float4(a.z, b.z, a.w, b.w);
}

// ---------------- sort ----------------
__device__ __forceinline__ int cell_id(float x, float y, float z)
{
    int cx = min(max((int)((x + 1.0f) * 8.0f), 0), 15);
    int cy = min(max((int)((y + 1.0f) * 8.0f), 0), 15);
    int cz = min(max((int)((z + 1.0f) * 8.0f), 0), 15);
    int c = 0;
    #pragma unroll
    for (int b = 0; b < 4; ++b)
        c |= (((cx >> b) & 1) << (3 * b))
           | (((cy >> b) & 1) << (3 * b + 1))
           | (((cz >> b) & 1) << (3 * b + 2));
    return c;
}

__global__ __launch_bounds__(256) void zero_hist(int* __restrict__ hist)
{
    hist[blockIdx.x * 256 + threadIdx.x] = 0;   // 16 blocks -> 4096 ints
}

__global__ __launch_bounds__(256) void hist_kernel(
    const float* __restrict__ xs, int* __restrict__ hist)
{
    int n = blockIdx.x * 256 + threadIdx.x;
    float x = xs[n * 3 + 0], y = xs[n * 3 + 1], z = xs[n * 3 + 2];
    atomicAdd(&hist[cell_id(x, y, z)], 1);
}

__global__ __launch_bounds__(1024) void scan_kernel(
    const int* __restrict__ hist, int* __restrict__ off)
{
    __shared__ int part[1024];
    int t = threadIdx.x;
    int4 h = reinterpret_cast<const int4*>(hist)[t];
    int s = h.x + h.y + h.z + h.w;
    part[t] = s;
    __syncthreads();
    for (int d = 1; d < 1024; d <<= 1) {
        int v = (t >= d) ? part[t - d] : 0;
        __syncthreads();
        part[t] += v;
        __syncthreads();
    }
    int excl = part[t] - s;          // exclusive prefix of this thread's 4
    int4 o;
    o.x = excl;
    o.y = o.x + h.x;
    o.z = o.y + h.y;
    o.w = o.z + h.z;
    reinterpret_cast<int4*>(off)[t] = o;
}

__global__ __launch_bounds__(256) void scatter_kernel(
    const float* __restrict__ xs, int* __restrict__ off,
    float4* __restrict__ sorted)
{
    int n = blockIdx.x * 256 + threadIdx.x;
    float x = xs[n * 3 + 0], y = xs[n * 3 + 1], z = xs[n * 3 + 2];
    int c = cell_id(x, y, z);
    int pos = atomicAdd(&off[c], 1);
    sorted[pos] = make_float4(x, y, z, __int_as_float(n));
}

// ---------------- sorted sample ----------------
template <bool PACKED>
__global__ __launch_bounds__(256) void sample_sorted(
    const float4* __restrict__ sorted, const float* __restrict__ Ms,
    const float* __restrict__ grids, float* __restrict__ out)
{
    int blk = blockIdx.x;
    // XCD-chunked swizzle: XCD k (= blk&7, round-robin dispatch) gets the
    // contiguous morton chunk range [k*128, (k+1)*128) -> L2 locality.
    int chunk = ((blk & 7) << 7) + (blk >> 3);

    float4 sp = sorted[chunk * 256 + threadIdx.x];
    const float cx = sp.x, cy = sp.y, cz = sp.z;
    const int n = __float_as_int(sp.w);
    float4* outr = reinterpret_cast<float4*>(out + (size_t)n * 128);

    for (int p = 0; p < 8; ++p) {           // 8 phases x 8 grids
        float2 acc[8];
        #pragma unroll
        for (int gg = 0; gg < 8; ++gg) {
            const int g = p * 8 + gg;
            const float* Mg = Ms + g * 16;  // wave-uniform -> s_load
            const float px = (fmaf(Mg[0], cx, fmaf(Mg[1], cy, fmaf(Mg[2],  cz, Mg[3])))  + 1.0f) * 31.5f;
            const float py = (fmaf(Mg[4], cx, fmaf(Mg[5], cy, fmaf(Mg[6],  cz, Mg[7])))  + 1.0f) * 31.5f;
            const float pz = (fmaf(Mg[8], cx, fmaf(Mg[9], cy, fmaf(Mg[10], cz, Mg[11]))) + 1.0f) * 31.5f;

            const float flx = floorf(px), fly = floorf(py), flz = floorf(pz);
            const float fx = px - flx, fy = py - fly, fz = pz - flz;
            const int x0 = (int)flx, y0 = (int)fly, z0 = (int)flz;

            const float wx0 = (x0 >= 0  && x0 < 64) ? (1.0f - fx) : 0.0f;
            const float wx1 = (x0 >= -1 && x0 < 63) ? fx          : 0.0f;
            const float wy0 = (y0 >= 0  && y0 < 64) ? (1.0f - fy) : 0.0f;
            const float wy1 = (y0 >= -1 && y0 < 63) ? fy          : 0.0f;
            const float wz0 = (z0 >= 0  && z0 < 64) ? (1.0f - fz) : 0.0f;
            const float wz1 = (z0 >= -1 && z0 < 63) ? fz          : 0.0f;

            const int xc0 = min(max(x0, 0), 63), xc1 = min(max(x0 + 1, 0), 63);
            const int yc0 = min(max(y0, 0), 63), yc1 = min(max(y0 + 1, 0), 63);
            const int zc0 = min(max(z0, 0), 63), zc1 = min(max(z0 + 1, 0), 63);

            const int r00 = (zc0 * 64 + yc0) * 64, r01 = (zc0 * 64 + yc1) * 64;
            const int r10 = (zc1 * 64 + yc0) * 64, r11 = (zc1 * 64 + yc1) * 64;

            const float waa = wz0 * wy0, wab = wz0 * wy1;
            const float wba = wz1 * wy0, wbb = wz1 * wy1;
            const float pA0 = waa * wx0, pA1 = waa * wx1;
            const float pB0 = wab * wx0, pB1 = wab * wx1;
            const float pC0 = wba * wx0, pC1 = wba * wx1;
            const float pD0 = wbb * wx0, pD1 = wbb * wx1;

            float a0, a1;
            if constexpr (PACKED) {
                const float2* gp = reinterpret_cast<const float2*>(grids) + (size_t)g * GVOX;
                const float2 vA0 = gp[r00 + xc0], vA1 = gp[r00 + xc1];
                const float2 vB0 = gp[r01 + xc0], vB1 = gp[r01 + xc1];
                const float2 vC0 = gp[r10 + xc0], vC1 = gp[r10 + xc1];
                const float2 vD0 = gp[r11 + xc0], vD1 = gp[r11 + xc1];
                a0 = vA0.x * pA0 + vA1.x * pA1 + vB0.x * pB0 + vB1.x * pB1
                   + vC0.x * pC0 + vC1.x * pC1 + vD0.x * pD0 + vD1.x * pD1;
                a1 = vA0.y * pA0 + vA1.y * pA1 + vB0.y * pB0 + vB1.y * pB1
                   + vC0.y * pC0 + vC1.y * pC1 + vD0.y * pD0 + vD1.y * pD1;
            } else {
                const float* g0 = grids + (size_t)g * 2 * GVOX;
                const float* g1 = g0 + GVOX;
                a0 = g0[r00 + xc0] * pA0 + g0[r00 + xc1] * pA1
                   + g0[r01 + xc0] * pB0 + g0[r01 + xc1] * pB1
                   + g0[r10 + xc0] * pC0 + g0[r10 + xc1] * pC1
                   + g0[r11 + xc0] * pD0 + g0[r11 + xc1] * pD1;
                a1 = g1[r00 + xc0] * pA0 + g1[r00 + xc1] * pA1
                   + g1[r01 + xc0] * pB0 + g1[r01 + xc1] * pB1
                   + g1[r10 + xc0] * pC0 + g1[r10 + xc1] * pC1
                   + g1[r11 + xc0] * pD0 + g1[r11 + xc1] * pD1;
            }
            acc[gg] = make_float2(a0, a1);
        }
        // One fully-written 64B line per thread-phase (offset n*512 + p*64).
        outr[p * 4 + 0] = make_float4(acc[0].x, acc[0].y, acc[1].x, acc[1].y);
        outr[p * 4 + 1] = make_float4(acc[2].x, acc[2].y, acc[3].x, acc[3].y);
        outr[p * 4 + 2] = make_float4(acc[4].x, acc[4].y, acc[5].x, acc[5].y);
        outr[p * 4 + 3] = make_float4(acc[6].x, acc[6].y, acc[7].x, acc[7].y);
    }
}

// ---------------- unsorted fallback (round-1 kernel) ----------------
template <bool PACKED>
__global__ __launch_bounds__(256) void sample_kernel(
    const float* __restrict__ xs, const float* __restrict__ Ms,
    const float* __restrict__ grids, float* __restrict__ out)
{
    const int g   = threadIdx.x & 63;
    const int wid = threadIdx.x >> 6;
    const float* Mg = Ms + g * 16;
    const float m00 = Mg[0], m01 = Mg[1], m02 = Mg[2],  m03 = Mg[3];
    const float m10 = Mg[4], m11 = Mg[5], m12 = Mg[6],  m13 = Mg[7];
    const float m20 = Mg[8], m21 = Mg[9], m22 = Mg[10], m23 = Mg[11];
    const float2* __restrict__ gp = reinterpret_cast<const float2*>(grids) + (size_t)g * GVOX;
    const float*  __restrict__ g0 = grids + (size_t)g * 2 * GVOX;
    const float*  __restrict__ g1 = g0 + GVOX;
    const int n0 = blockIdx.x * 32 + wid * 8;
    #pragma unroll
    for (int i = 0; i < 8; ++i) {
        const int n = n0 + i;
        const float cx = xs[n * 3 + 0], cy = xs[n * 3 + 1], cz = xs[n * 3 + 2];
        const float px = (fmaf(m00, cx, fmaf(m01, cy, fmaf(m02, cz, m03))) + 1.0f) * 31.5f;
        const float py = (fmaf(m10, cx, fmaf(m11, cy, fmaf(m12, cz, m13))) + 1.0f) * 31.5f;
        const float pz = (fmaf(m20, cx, fmaf(m21, cy, fmaf(m22, cz, m23))) + 1.0f) * 31.5f;
        const float flx = floorf(px), fly = floorf(py), flz = floorf(pz);
        const float fx = px - flx, fy = py - fly, fz = pz - flz;
        const int x0 = (int)flx, y0 = (int)fly, z0 = (int)flz;
        const float wx0 = (x0 >= 0  && x0 < 64) ? (1.0f - fx) : 0.0f;
        const float wx1 = (x0 >= -1 && x0 < 63) ? fx          : 0.0f;
        const float wy0 = (y0 >= 0  && y0 < 64) ? (1.0f - fy) : 0.0f;
        const float wy1 = (y0 >= -1 && y0 < 63) ? fy          : 0.0f;
        const float wz0 = (z0 >= 0  && z0 < 64) ? (1.0f - fz) : 0.0f;
        const float wz1 = (z0 >= -1 && z0 < 63) ? fz          : 0.0f;
        const int xc0 = min(max(x0, 0), 63), xc1 = min(max(x0 + 1, 0), 63);
        const int yc0 = min(max(y0, 0), 63), yc1 = min(max(y0 + 1, 0), 63);
        const int zc0 = min(max(z0, 0), 63), zc1 = min(max(z0 + 1, 0), 63);
        const int r00 = (zc0 * 64 + yc0) * 64, r01 = (zc0 * 64 + yc1) * 64;
        const int r10 = (zc1 * 64 + yc0) * 64, r11 = (zc1 * 64 + yc1) * 64;
        const float waa = wz0 * wy0, wab = wz0 * wy1;
        const float wba = wz1 * wy0, wbb = wz1 * wy1;
        const float pA0 = waa * wx0, pA1 = waa * wx1;
        const float pB0 = wab * wx0, pB1 = wab * wx1;
        const float pC0 = wba * wx0, pC1 = wba * wx1;
        const float pD0 = wbb * wx0, pD1 = wbb * wx1;
        float acc0, acc1;
        if constexpr (PACKED) {
            const float2 vA0 = gp[r00 + xc0], vA1 = gp[r00 + xc1];
            const float2 vB0 = gp[r01 + xc0], vB1 = gp[r01 + xc1];
            const float2 vC0 = gp[r10 + xc0], vC1 = gp[r10 + xc1];
            const float2 vD0 = gp[r11 + xc0], vD1 = gp[r11 + xc1];
            acc0 = vA0.x * pA0 + vA1.x * pA1 + vB0.x * pB0 + vB1.x * pB1
                 + vC0.x * pC0 + vC1.x * pC1 + vD0.x * pD0 + vD1.x * pD1;
            acc1 = vA0.y * pA0 + vA1.y * pA1 + vB0.y * pB0 + vB1.y * pB1
                 + vC0.y * pC0 + vC1.y * pC1 + vD0.y * pD0 + vD1.y * pD1;
        } else {
            acc0 = g0[r00 + xc0] * pA0 + g0[r00 + xc1] * pA1
                 + g0[r01 + xc0] * pB0 + g0[r01 + xc1] * pB1
                 + g0[r10 + xc0] * pC0 + g0[r10 + xc1] * pC1
                 + g0[r11 + xc0] * pD0 + g0[r11 + xc1] * pD1;
            acc1 = g1[r00 + xc0] * pA0 + g1[r00 + xc1] * pA1
                 + g1[r01 + xc0] * pB0 + g1[r01 + xc1] * pB1
                 + g1[r10 + xc0] * pC0 + g1[r10 + xc1] * pC1
                 + g1[r11 + xc0] * pD0 + g1[r11 + xc1] * pD1;
        }
        *reinterpret_cast<float2*>(out + (size_t)n * 128 + g * 2) =
            make_float2(acc0, acc1);
    }
}

// ---------------- launch ----------------
extern "C" void kernel_launch(void* const* d_in, const int* in_sizes, int n_in,
                              void* d_out, int out_size, void* d_ws, size_t ws_size,
                              hipStream_t stream)
{
    const float* xs = (const float*)d_in[0];
    const float* Ms = (const float*)d_in[1];
    const float* fg = (const float*)d_in[2];
    float* out = (float*)d_out;
    char* ws = (char*)d_ws;

    const size_t SORTED_BYTES = (size_t)NPTS * 16;            // 4 MB
    const size_t HIST_OFF = SORTED_BYTES;                     // +16 KB
    const size_t OFF_OFF  = HIST_OFF + (size_t)NCELL * 4;     // +16 KB
    const size_t PACK_OFF = (size_t)8 << 20;                  // 8 MB
    const size_t PACK_BYTES = (size_t)64 * GVOX * 8;          // 134 MB

    const bool can_sort = ws_size >= PACK_OFF;
    const bool can_pack_sorted = ws_size >= PACK_OFF + PACK_BYTES;
    const bool can_pack_plain  = ws_size >= PACK_BYTES;

    if (can_sort) {
        int* hist = (int*)(ws + HIST_OFF);
        int* off  = (int*)(ws + OFF_OFF);
        float4* sorted = (float4*)ws;
        zero_hist<<<16, 256, 0, stream>>>(hist);
        hist_kernel<<<NPTS / 256, 256, 0, stream>>>(xs, hist);
        scan_kernel<<<1, 1024, 0, stream>>>(hist, off);
        scatter_kernel<<<NPTS / 256, 256, 0, stream>>>(xs, off, sorted);
        if (can_pack_sorted) {
            repack_kernel<<<16384, 256, 0, stream>>>(fg, (float4*)(ws + PACK_OFF));
            sample_sorted<true><<<NPTS / 256, 256, 0, stream>>>(
                sorted, Ms, (const float*)(ws + PACK_OFF), out);
        } else {
            sample_sorted<false><<<NPTS / 256, 256, 0, stream>>>(
                sorted, Ms, fg, out);
        }
    } else if (can_pack_plain) {
        repack_kernel<<<16384, 256, 0, stream>>>(fg, (float4*)d_ws);
        sample_kernel<true><<<NPTS / 32, 256, 0, stream>>>(
            xs, Ms, (const float*)d_ws, out);
    } else {
        sample_kernel<false><<<NPTS / 32, 256, 0, stream>>>(xs, Ms, fg, out);
    }
}

// Round 5
// 547.546 us; speedup vs baseline: 2.5363x; 1.0915x over previous
//
#include <hip/hip_runtime.h>

// AMG encoder: 262144 points x 64 grids x 2 features, trilinear grid_sample
// (align_corners=True, zero padding), out[n, g*2+f] f32.
//
// Pipeline:
//   1. repack grids [G,F,D,H,W] -> [G,D,H,W,F] (float2/voxel) in ws
//   2. morton-sort points into 16^3 cells (memset -> hist -> scan -> scatter)
//   3. sample: block = (256 sorted points) x (16 grids via blockIdx.y);
//      4 x 16B gather per (point,grid) [x-pair as one dwordx4];
//      32-float register row accumulate -> one 128B nontemporal write.

constexpr int NPTS  = 262144;
constexpr int GVOX  = 64 * 64 * 64;
constexpr int NCELL = 4096;            // 16^3 morton cells
constexpr int GSPLIT = 4;              // grid quarters (16 grids each)

typedef float f32x4 __attribute__((ext_vector_type(4)));  // for nontemporal stores

// ---------------- repack ----------------
__global__ __launch_bounds__(256) void repack_kernel(
    const float* __restrict__ src, float4* __restrict__ dst)
{
    int tid = blockIdx.x * 256 + threadIdx.x;
    int g = tid >> 16;
    int q = tid & 65535;
    const float* p0 = src + (size_t)g * (2 * GVOX) + q * 4;
    float4 a = *reinterpret_cast<const float4*>(p0);
    float4 b = *reinterpret_cast<const float4*>(p0 + GVOX);
    float4* o = dst + (((size_t)g * GVOX) >> 1) + (size_t)q * 2;
    o[0] = make_float4(a.x, b.x, a.y, b.y);
    o[1] = make_float4(a.z, b.z, a.w, b.w);
}

// ---------------- sort ----------------
__device__ __forceinline__ int cell_id(float x, float y, float z)
{
    int cx = min(max((int)((x + 1.0f) * 8.0f), 0), 15);
    int cy = min(max((int)((y + 1.0f) * 8.0f), 0), 15);
    int cz = min(max((int)((z + 1.0f) * 8.0f), 0), 15);
    int c = 0;
    #pragma unroll
    for (int b = 0; b < 4; ++b)
        c |= (((cx >> b) & 1) << (3 * b))
           | (((cy >> b) & 1) << (3 * b + 1))
           | (((cz >> b) & 1) << (3 * b + 2));
    return c;
}

__global__ __launch_bounds__(256) void hist_kernel(
    const float* __restrict__ xs, int* __restrict__ hist)
{
    int n = blockIdx.x * 256 + threadIdx.x;
    float x = xs[n * 3 + 0], y = xs[n * 3 + 1], z = xs[n * 3 + 2];
    atomicAdd(&hist[cell_id(x, y, z)], 1);
}

__global__ __launch_bounds__(1024) void scan_kernel(
    const int* __restrict__ hist, int* __restrict__ off)
{
    __shared__ int part[1024];
    int t = threadIdx.x;
    int4 h = reinterpret_cast<const int4*>(hist)[t];
    int s = h.x + h.y + h.z + h.w;
    part[t] = s;
    __syncthreads();
    for (int d = 1; d < 1024; d <<= 1) {
        int v = (t >= d) ? part[t - d] : 0;
        __syncthreads();
        part[t] += v;
        __syncthreads();
    }
    int excl = part[t] - s;
    int4 o;
    o.x = excl;
    o.y = o.x + h.x;
    o.z = o.y + h.y;
    o.w = o.z + h.z;
    reinterpret_cast<int4*>(off)[t] = o;
}

__global__ __launch_bounds__(256) void scatter_kernel(
    const float* __restrict__ xs, int* __restrict__ off,
    float4* __restrict__ sorted)
{
    int n = blockIdx.x * 256 + threadIdx.x;
    float x = xs[n * 3 + 0], y = xs[n * 3 + 1], z = xs[n * 3 + 2];
    int c = cell_id(x, y, z);
    int pos = atomicAdd(&off[c], 1);
    sorted[pos] = make_float4(x, y, z, __int_as_float(n));
}

// ---------------- sorted sample: 16 grids/block, register row ----------------
template <bool PACKED>
__global__ __launch_bounds__(256) void sample_sorted(
    const float4* __restrict__ sorted, const float* __restrict__ Ms,
    const float* __restrict__ grids, float* __restrict__ out)
{
    const int blk = blockIdx.x;
    // XCD-chunked swizzle (1024 x-blocks, 8 XCDs round-robin on linear id;
    // gridDim.x*y keeps x%8 == XCD for every y-slice).
    const int chunk = ((blk & 7) << 7) + (blk >> 3);
    const int gbase = blockIdx.y * 16;

    const float4 sp = sorted[chunk * 256 + threadIdx.x];
    const float cx = sp.x, cy = sp.y, cz = sp.z;
    const int n = __float_as_int(sp.w);

    float2 acc[16];

    #pragma unroll
    for (int gg = 0; gg < 16; ++gg) {
        const int g = gbase + gg;
        const float* Mg = Ms + g * 16;   // wave-uniform -> s_load
        const float px = (fmaf(Mg[0], cx, fmaf(Mg[1], cy, fmaf(Mg[2],  cz, Mg[3])))  + 1.0f) * 31.5f;
        const float py = (fmaf(Mg[4], cx, fmaf(Mg[5], cy, fmaf(Mg[6],  cz, Mg[7])))  + 1.0f) * 31.5f;
        const float pz = (fmaf(Mg[8], cx, fmaf(Mg[9], cy, fmaf(Mg[10], cz, Mg[11]))) + 1.0f) * 31.5f;

        const float flx = floorf(px), fly = floorf(py), flz = floorf(pz);
        const float fx = px - flx, fy = py - fly, fz = pz - flz;
        const int x0 = (int)flx, y0 = (int)fly, z0 = (int)flz;

        // Per-axis weights with zero-padding validity folded in.
        const float wx0 = (x0 >= 0  && x0 < 64) ? (1.0f - fx) : 0.0f;
        const float wx1 = (x0 >= -1 && x0 < 63) ? fx          : 0.0f;
        const float wy0 = (y0 >= 0  && y0 < 64) ? (1.0f - fy) : 0.0f;
        const float wy1 = (y0 >= -1 && y0 < 63) ? fy          : 0.0f;
        const float wz0 = (z0 >= 0  && z0 < 64) ? (1.0f - fz) : 0.0f;
        const float wz1 = (z0 >= -1 && z0 < 63) ? fz          : 0.0f;

        const int yc0 = min(max(y0, 0), 63), yc1 = min(max(y0 + 1, 0), 63);
        const int zc0 = min(max(z0, 0), 63), zc1 = min(max(z0 + 1, 0), 63);
        const int r00 = (zc0 * 64 + yc0) * 64, r01 = (zc0 * 64 + yc1) * 64;
        const int r10 = (zc1 * 64 + yc0) * 64, r11 = (zc1 * 64 + yc1) * 64;

        const float waa = wz0 * wy0, wab = wz0 * wy1;
        const float wba = wz1 * wy0, wbb = wz1 * wy1;

        float a0, a1;
        if constexpr (PACKED) {
            // x-pair (xa, xa+1) fetched as one 16B load; base clamped to
            // [0,62] so loads never leave the row. Boundary corners fixed
            // up by branchless selects (their weights are already 0/valid).
            const int xa = min(max(x0, 0), 62);
            const bool hiSel = (x0 >= 63);   // corner0 = element 1
            const bool loSel = (x0 < 0);     // corner1 = element 0
            const float2* gp = reinterpret_cast<const float2*>(grids) + (size_t)g * GVOX;

            const float4 vA = *reinterpret_cast<const float4*>(gp + (r00 + xa));
            const float4 vB = *reinterpret_cast<const float4*>(gp + (r01 + xa));
            const float4 vC = *reinterpret_cast<const float4*>(gp + (r10 + xa));
            const float4 vD = *reinterpret_cast<const float4*>(gp + (r11 + xa));

            const float2 cA0 = hiSel ? make_float2(vA.z, vA.w) : make_float2(vA.x, vA.y);
            const float2 cA1 = loSel ? make_float2(vA.x, vA.y) : make_float2(vA.z, vA.w);
            const float2 cB0 = hiSel ? make_float2(vB.z, vB.w) : make_float2(vB.x, vB.y);
            const float2 cB1 = loSel ? make_float2(vB.x, vB.y) : make_float2(vB.z, vB.w);
            const float2 cC0 = hiSel ? make_float2(vC.z, vC.w) : make_float2(vC.x, vC.y);
            const float2 cC1 = loSel ? make_float2(vC.x, vC.y) : make_float2(vC.z, vC.w);
            const float2 cD0 = hiSel ? make_float2(vD.z, vD.w) : make_float2(vD.x, vD.y);
            const float2 cD1 = loSel ? make_float2(vD.x, vD.y) : make_float2(vD.z, vD.w);

            const float pA0 = waa * wx0, pA1 = waa * wx1;
            const float pB0 = wab * wx0, pB1 = wab * wx1;
            const float pC0 = wba * wx0, pC1 = wba * wx1;
            const float pD0 = wbb * wx0, pD1 = wbb * wx1;

            a0 = cA0.x * pA0 + cA1.x * pA1 + cB0.x * pB0 + cB1.x * pB1
               + cC0.x * pC0 + cC1.x * pC1 + cD0.x * pD0 + cD1.x * pD1;
            a1 = cA0.y * pA0 + cA1.y * pA1 + cB0.y * pB0 + cB1.y * pB1
               + cC0.y * pC0 + cC1.y * pC1 + cD0.y * pD0 + cD1.y * pD1;
        } else {
            const int xc0 = min(max(x0, 0), 63), xc1 = min(max(x0 + 1, 0), 63);
            const float pA0 = waa * wx0, pA1 = waa * wx1;
            const float pB0 = wab * wx0, pB1 = wab * wx1;
            const float pC0 = wba * wx0, pC1 = wba * wx1;
            const float pD0 = wbb * wx0, pD1 = wbb * wx1;
            const float* g0 = grids + (size_t)g * 2 * GVOX;
            const float* g1 = g0 + GVOX;
            a0 = g0[r00 + xc0] * pA0 + g0[r00 + xc1] * pA1
               + g0[r01 + xc0] * pB0 + g0[r01 + xc1] * pB1
               + g0[r10 + xc0] * pC0 + g0[r10 + xc1] * pC1
               + g0[r11 + xc0] * pD0 + g0[r11 + xc1] * pD1;
            a1 = g1[r00 + xc0] * pA0 + g1[r00 + xc1] * pA1
               + g1[r01 + xc0] * pB0 + g1[r01 + xc1] * pB1
               + g1[r10 + xc0] * pC0 + g1[r10 + xc1] * pC1
               + g1[r11 + xc0] * pD0 + g1[r11 + xc1] * pD1;
        }
        acc[gg] = make_float2(a0, a1);
    }

    // One contiguous 128B-aligned 128B row chunk, nontemporal (don't pollute
    // L2 that the gathers need).
    f32x4* outr = reinterpret_cast<f32x4*>(out + (size_t)n * 128 + gbase * 2);
    #pragma unroll
    for (int q = 0; q < 8; ++q) {
        f32x4 v = { acc[2 * q].x, acc[2 * q].y, acc[2 * q + 1].x, acc[2 * q + 1].y };
        __builtin_nontemporal_store(v, &outr[q]);
    }
}

// ---------------- unsorted fallback ----------------
template <bool PACKED>
__global__ __launch_bounds__(256) void sample_kernel(
    const float* __restrict__ xs, const float* __restrict__ Ms,
    const float* __restrict__ grids, float* __restrict__ out)
{
    const int g   = threadIdx.x & 63;
    const int wid = threadIdx.x >> 6;
    const float* Mg = Ms + g * 16;
    const float m00 = Mg[0], m01 = Mg[1], m02 = Mg[2],  m03 = Mg[3];
    const float m10 = Mg[4], m11 = Mg[5], m12 = Mg[6],  m13 = Mg[7];
    const float m20 = Mg[8], m21 = Mg[9], m22 = Mg[10], m23 = Mg[11];
    const float2* __restrict__ gp = reinterpret_cast<const float2*>(grids) + (size_t)g * GVOX;
    const float*  __restrict__ g0 = grids + (size_t)g * 2 * GVOX;
    const float*  __restrict__ g1 = g0 + GVOX;
    const int n0 = blockIdx.x * 32 + wid * 8;
    #pragma unroll
    for (int i = 0; i < 8; ++i) {
        const int n = n0 + i;
        const float cx = xs[n * 3 + 0], cy = xs[n * 3 + 1], cz = xs[n * 3 + 2];
        const float px = (fmaf(m00, cx, fmaf(m01, cy, fmaf(m02, cz, m03))) + 1.0f) * 31.5f;
        const float py = (fmaf(m10, cx, fmaf(m11, cy, fmaf(m12, cz, m13))) + 1.0f) * 31.5f;
        const float pz = (fmaf(m20, cx, fmaf(m21, cy, fmaf(m22, cz, m23))) + 1.0f) * 31.5f;
        const float flx = floorf(px), fly = floorf(py), flz = floorf(pz);
        const float fx = px - flx, fy = py - fly, fz = pz - flz;
        const int x0 = (int)flx, y0 = (int)fly, z0 = (int)flz;
        const float wx0 = (x0 >= 0  && x0 < 64) ? (1.0f - fx) : 0.0f;
        const float wx1 = (x0 >= -1 && x0 < 63) ? fx          : 0.0f;
        const float wy0 = (y0 >= 0  && y0 < 64) ? (1.0f - fy) : 0.0f;
        const float wy1 = (y0 >= -1 && y0 < 63) ? fy          : 0.0f;
        const float wz0 = (z0 >= 0  && z0 < 64) ? (1.0f - fz) : 0.0f;
        const float wz1 = (z0 >= -1 && z0 < 63) ? fz          : 0.0f;
        const int xc0 = min(max(x0, 0), 63), xc1 = min(max(x0 + 1, 0), 63);
        const int yc0 = min(max(y0, 0), 63), yc1 = min(max(y0 + 1, 0), 63);
        const int zc0 = min(max(z0, 0), 63), zc1 = min(max(z0 + 1, 0), 63);
        const int r00 = (zc0 * 64 + yc0) * 64, r01 = (zc0 * 64 + yc1) * 64;
        const int r10 = (zc1 * 64 + yc0) * 64, r11 = (zc1 * 64 + yc1) * 64;
        const float waa = wz0 * wy0, wab = wz0 * wy1;
        const float wba = wz1 * wy0, wbb = wz1 * wy1;
        const float pA0 = waa * wx0, pA1 = waa * wx1;
        const float pB0 = wab * wx0, pB1 = wab * wx1;
        const float pC0 = wba * wx0, pC1 = wba * wx1;
        const float pD0 = wbb * wx0, pD1 = wbb * wx1;
        float acc0, acc1;
        if constexpr (PACKED) {
            const float2 vA0 = gp[r00 + xc0], vA1 = gp[r00 + xc1];
            const float2 vB0 = gp[r01 + xc0], vB1 = gp[r01 + xc1];
            const float2 vC0 = gp[r10 + xc0], vC1 = gp[r10 + xc1];
            const float2 vD0 = gp[r11 + xc0], vD1 = gp[r11 + xc1];
            acc0 = vA0.x * pA0 + vA1.x * pA1 + vB0.x * pB0 + vB1.x * pB1
                 + vC0.x * pC0 + vC1.x * pC1 + vD0.x * pD0 + vD1.x * pD1;
            acc1 = vA0.y * pA0 + vA1.y * pA1 + vB0.y * pB0 + vB1.y * pB1
                 + vC0.y * pC0 + vC1.y * pC1 + vD0.y * pD0 + vD1.y * pD1;
        } else {
            acc0 = g0[r00 + xc0] * pA0 + g0[r00 + xc1] * pA1
                 + g0[r01 + xc0] * pB0 + g0[r01 + xc1] * pB1
                 + g0[r10 + xc0] * pC0 + g0[r10 + xc1] * pC1
                 + g0[r11 + xc0] * pD0 + g0[r11 + xc1] * pD1;
            acc1 = g1[r00 + xc0] * pA0 + g1[r00 + xc1] * pA1
                 + g1[r01 + xc0] * pB0 + g1[r01 + xc1] * pB1
                 + g1[r10 + xc0] * pC0 + g1[r10 + xc1] * pC1
                 + g1[r11 + xc0] * pD0 + g1[r11 + xc1] * pD1;
        }
        *reinterpret_cast<float2*>(out + (size_t)n * 128 + g * 2) =
            make_float2(acc0, acc1);
    }
}

// ---------------- launch ----------------
extern "C" void kernel_launch(void* const* d_in, const int* in_sizes, int n_in,
                              void* d_out, int out_size, void* d_ws, size_t ws_size,
                              hipStream_t stream)
{
    const float* xs = (const float*)d_in[0];
    const float* Ms = (const float*)d_in[1];
    const float* fg = (const float*)d_in[2];
    float* out = (float*)d_out;
    char* ws = (char*)d_ws;

    const size_t SORTED_BYTES = (size_t)NPTS * 16;            // 4 MB
    const size_t HIST_OFF = SORTED_BYTES;                     // +16 KB
    const size_t OFF_OFF  = HIST_OFF + (size_t)NCELL * 4;     // +16 KB
    const size_t PACK_OFF = (size_t)8 << 20;                  // 8 MB
    const size_t PACK_BYTES = (size_t)64 * GVOX * 8;          // 134 MB

    const bool can_sort = ws_size >= PACK_OFF;
    const bool can_pack_sorted = ws_size >= PACK_OFF + PACK_BYTES;
    const bool can_pack_plain  = ws_size >= PACK_BYTES;

    if (can_sort) {
        int* hist = (int*)(ws + HIST_OFF);
        int* off  = (int*)(ws + OFF_OFF);
        float4* sorted = (float4*)ws;
        (void)hipMemsetAsync(hist, 0, NCELL * 4, stream);
        hist_kernel<<<NPTS / 256, 256, 0, stream>>>(xs, hist);
        scan_kernel<<<1, 1024, 0, stream>>>(hist, off);
        scatter_kernel<<<NPTS / 256, 256, 0, stream>>>(xs, off, sorted);
        if (can_pack_sorted) {
            repack_kernel<<<16384, 256, 0, stream>>>(fg, (float4*)(ws + PACK_OFF));
            sample_sorted<true><<<dim3(NPTS / 256, GSPLIT), 256, 0, stream>>>(
                sorted, Ms, (const float*)(ws + PACK_OFF), out);
        } else {
            sample_sorted<false><<<dim3(NPTS / 256, GSPLIT), 256, 0, stream>>>(
                sorted, Ms, fg, out);
        }
    } else if (can_pack_plain) {
        repack_kernel<<<16384, 256, 0, stream>>>(fg, (float4*)d_ws);
        sample_kernel<true><<<NPTS / 32, 256, 0, stream>>>(
            xs, Ms, (const float*)d_ws, out);
    } else {
        sample_kernel<false><<<NPTS / 32, 256, 0, stream>>>(xs, Ms, fg, out);
    }
}